// Round 14
// baseline (182.994 us; speedup 1.0000x reference)
//
#include <hip/hip_runtime.h>
#include <hip/hip_bf16.h>

// B=512, S=16384, C=3. logits f32 [B,S,3], labels i32 [B,S].
// out = mean over valid of ( -w[lab]*logp[lab] - 2.0*(true_sw & pred_near)
//                            + 1.5*(pred_sw & ~true_near & has_true_row & valid) )
// TOL=5 window, per-row edge-clipped.
//
// R13 post-mortem: LDS-stage+barrier streaming caps at ~2.4 TB/s (barrier
// drains expose full HBM latency; compute between barriers too thin).
// Harness fills run at 6.7 TB/s on the same chip. So: NO LDS, NO barriers
// in the stream path — direct register compute, deep-unrolled independent
// loads (16/wave in flight), persistent grid-stride blocks. Masks via
// global (3MB) as in R2/R6. No global atomics (R2: f64 CAS ~200us).

#define TOL 5
#define BLOCK 256
#define CHUNK 1024
#define GRID1 2048            // persistent blocks: 8/CU on 256 CUs

typedef unsigned long long u64;

// ---------------- K1: direct-register streaming pass ----------------
__global__ __launch_bounds__(BLOCK) void k1_direct(
    const float* __restrict__ logits, const int* __restrict__ labels,
    u64* __restrict__ pmask, u64* __restrict__ tmask, u64* __restrict__ vmask,
    double* __restrict__ pbsum, int* __restrict__ pvcnt, long long nchunk)
{
    const int tid = threadIdx.x;
    const int wave = tid >> 6;

    float bsum = 0.f;
    int   vcnt = 0;

    for (long long c = blockIdx.x; c < nchunk; c += GRID1) {
        const long long base = c * CHUNK;
#pragma unroll
        for (int q = 0; q < CHUNK / BLOCK; ++q) {
            const long long p = base + q * BLOCK + tid;
            // dwordx3 logits + dword label, straight to registers (coalesced)
            const float l0 = logits[3 * p + 0];
            const float l1 = logits[3 * p + 1];
            const float l2 = logits[3 * p + 2];
            const int lab = labels[p];

            const bool valid = (lab != -100);
            const int ls = valid ? lab : 0;

            const float mx = fmaxf(l0, fmaxf(l1, l2));
            const float se = __expf(l0 - mx) + __expf(l1 - mx) + __expf(l2 - mx);
            const float lse = mx + __logf(se);
            const float lpick = (ls == 0 ? l0 : (ls == 1 ? l1 : l2)) - lse;
            const float w = (ls == 0) ? 0.1f : 5.0f;
            bsum += valid ? (-w * lpick) : 0.f;
            vcnt += valid ? 1 : 0;

            // argmax first-occurrence: pred>=1 iff max(l1,l2) > l0
            const bool psw = fmaxf(l1, l2) > l0;
            const bool tsw = (lab >= 1);           // -100 excluded

            const u64 pm = __ballot(psw);
            const u64 tm = __ballot(tsw);
            const u64 vm = __ballot(valid);
            if ((tid & 63) == 0) {
                const long long g = (base + q * BLOCK + wave * 64) >> 6;
                pmask[g] = pm; tmask[g] = tm; vmask[g] = vm;
            }
        }
    }

    // block reduce -> per-block partial (no atomics)
#pragma unroll
    for (int off = 32; off; off >>= 1) {
        bsum += __shfl_down(bsum, off);
        vcnt += __shfl_down(vcnt, off);
    }
    __shared__ float wb[BLOCK / 64];
    __shared__ int   wv[BLOCK / 64];
    if ((tid & 63) == 0) { wb[wave] = bsum; wv[wave] = vcnt; }
    __syncthreads();
    if (tid == 0) {
        double s = 0.0; int cc = 0;
#pragma unroll
        for (int i = 0; i < BLOCK / 64; ++i) { s += (double)wb[i]; cc += wv[i]; }
        pbsum[blockIdx.x] = s;
        pvcnt[blockIdx.x] = cc;
    }
}

// ---------------- K2: per-row window + counts ----------------
// One block per row, thread t owns 64-position group t (S/64 == 256 == BLOCK).
__global__ __launch_bounds__(BLOCK) void k2_window(
    const u64* __restrict__ pmask, const u64* __restrict__ tmask,
    const u64* __restrict__ vmask, float* __restrict__ adj_row)
{
    const int row = blockIdx.x;
    const int t = threadIdx.x;
    const int GPR = BLOCK;
    const long long base = (long long)row * GPR + t;

    const u64 pm = pmask[base];
    const u64 tm = tmask[base];
    const u64 vm = vmask[base];
    const u64 pp = (t > 0)       ? pmask[base - 1] : 0ULL;
    const u64 pn = (t < GPR - 1) ? pmask[base + 1] : 0ULL;
    const u64 tp = (t > 0)       ? tmask[base - 1] : 0ULL;
    const u64 tn = (t < GPR - 1) ? tmask[base + 1] : 0ULL;

    u64 pnear = pm, tnear = tm;
#pragma unroll
    for (int k = 1; k <= TOL; ++k) {
        pnear |= (pm << k) | (pm >> k) | (pp >> (64 - k)) | (pn << (64 - k));
        tnear |= (tm << k) | (tm >> k) | (tp >> (64 - k)) | (tn << (64 - k));
    }

    int reward  = __popcll(tm & pnear);        // true_sw implies valid
    int penalty = __popcll(pm & ~tnear & vm);  // gated by valid
    int ht = (tm != 0ULL) ? 1 : 0;

#pragma unroll
    for (int off = 32; off; off >>= 1) {
        reward  += __shfl_down(reward, off);
        penalty += __shfl_down(penalty, off);
        ht      |= __shfl_down(ht, off);
    }
    __shared__ int rs[BLOCK / 64], ps[BLOCK / 64], hs[BLOCK / 64];
    const int wave = t >> 6;
    if ((t & 63) == 0) { rs[wave] = reward; ps[wave] = penalty; hs[wave] = ht; }
    __syncthreads();
    if (t == 0) {
        int R = 0, P = 0, H = 0;
#pragma unroll
        for (int i = 0; i < BLOCK / 64; ++i) { R += rs[i]; P += ps[i]; H |= hs[i]; }
        adj_row[row] = -2.0f * (float)R + (H ? 1.5f * (float)P : 0.0f);  // exact ints
    }
}

// ---------------- K3: final reduce (one block) ----------------
__global__ __launch_bounds__(BLOCK) void k3_reduce(
    const double* __restrict__ pbsum, const int* __restrict__ pvcnt, int nblocks,
    const float* __restrict__ adj_row, int nrows,
    float* __restrict__ out)
{
    const int t = threadIdx.x;
    double s = 0.0, a = 0.0;
    long long c = 0;
    for (int i = t; i < nblocks; i += BLOCK) { s += pbsum[i]; c += (long long)pvcnt[i]; }
    for (int i = t; i < nrows; i += BLOCK) a += (double)adj_row[i];

#pragma unroll
    for (int off = 32; off; off >>= 1) {
        s += __shfl_down(s, off);
        a += __shfl_down(a, off);
        c += __shfl_down(c, off);
    }
    __shared__ double ss[BLOCK / 64], as[BLOCK / 64];
    __shared__ long long cs[BLOCK / 64];
    const int wave = t >> 6;
    if ((t & 63) == 0) { ss[wave] = s; as[wave] = a; cs[wave] = c; }
    __syncthreads();
    if (t == 0) {
        double S = 0.0, A = 0.0; long long C = 0;
#pragma unroll
        for (int i = 0; i < BLOCK / 64; ++i) { S += ss[i]; A += as[i]; C += cs[i]; }
        out[0] = (float)((S + A) / (double)C);
    }
}

extern "C" void kernel_launch(void* const* d_in, const int* in_sizes, int n_in,
                              void* d_out, int out_size, void* d_ws, size_t ws_size,
                              hipStream_t stream) {
    const float* logits = (const float*)d_in[0];
    const int*   labels = (const int*)d_in[1];
    float* out = (float*)d_out;

    const long long BS = in_sizes[1];        // B*S = 8388608
    const long long NGROUP = BS / 64;        // 131072
    const int B = 512;                       // rows (S=16384 -> 256 groups/row)
    const long long nchunk = BS / CHUNK;     // 8192

    char* ws = (char*)d_ws;
    u64* pmask = (u64*)ws;                               // 1 MB
    u64* tmask = pmask + NGROUP;                         // 1 MB
    u64* vmask = tmask + NGROUP;                         // 1 MB
    double* pbsum = (double*)(vmask + NGROUP);           // 16 KB
    int* pvcnt    = (int*)(pbsum + GRID1);               // 8 KB
    float* adjrow = (float*)(pvcnt + GRID1);             // 2 KB

    k1_direct<<<GRID1, BLOCK, 0, stream>>>(
        logits, labels, pmask, tmask, vmask, pbsum, pvcnt, nchunk);
    k2_window<<<B, BLOCK, 0, stream>>>(pmask, tmask, vmask, adjrow);
    k3_reduce<<<1, BLOCK, 0, stream>>>(pbsum, pvcnt, GRID1, adjrow, B, out);
}

// Round 15
// 178.480 us; speedup vs baseline: 1.0253x; 1.0253x over previous
//
#include <hip/hip_runtime.h>
#include <hip/hip_bf16.h>

// B=512, S=16384, C=3. logits f32 [B,S,3], labels i32 [B,S].
// out = mean over valid of ( -w[lab]*logp[lab] - 2.0*(true_sw & pred_near)
//                            + 1.5*(pred_sw & ~true_near & has_true_row & valid) )
// TOL=5 window, per-row edge-clipped.
//
// R14 post-mortem: k1 was latency/issue-bound (VGPR=24 -> compiler serialized
// load->wait->compute per position; stride-12 scalar gathers). Fix: 8 positions
// per thread, 6xfloat4 + 2xint4 batched into register arrays BEFORE compute
// (8 independent 16B loads in flight), nibble-packed mask bytes instead of
// ballot, no barriers in stream path, no global atomics (R2: f64 CAS ~200us).

#define TOL 5
#define BLOCK 256
#define GRID1 2048            // 8 blocks/CU on 256 CUs

typedef unsigned long long u64;
typedef unsigned short u16;
typedef unsigned char u8;

// ---------------- K1: 8-pos/thread direct streaming ----------------
__global__ __launch_bounds__(BLOCK) void k1_oct(
    const float* __restrict__ logits, const int* __restrict__ labels,
    u16* __restrict__ pt16, u16* __restrict__ v16,
    double* __restrict__ pbsum, int* __restrict__ pvcnt, long long nOct)
{
    const int tid = threadIdx.x;
    const int wave = tid >> 6;

    float bsum = 0.f;
    int   vcnt = 0;

    for (long long o = blockIdx.x; o < nOct; o += GRID1) {
        const long long p0 = o * (BLOCK * 8) + (long long)tid * 8;   // 8 consecutive positions

        // ---- batched loads: 6 float4 + 2 int4, all independent ----
        const float4* lf = (const float4*)(logits + 3 * p0);   // 24 floats, 96B-aligned
        const int4*   li = (const int4*)(labels + p0);         // 8 ints, 16B-aligned
        float4 f[6];
        int4   lb[2];
#pragma unroll
        for (int k = 0; k < 6; ++k) f[k] = lf[k];
        lb[0] = li[0]; lb[1] = li[1];

        float fl[24];
#pragma unroll
        for (int k = 0; k < 6; ++k) {
            fl[4 * k + 0] = f[k].x; fl[4 * k + 1] = f[k].y;
            fl[4 * k + 2] = f[k].z; fl[4 * k + 3] = f[k].w;
        }
        int labs[8] = { lb[0].x, lb[0].y, lb[0].z, lb[0].w,
                        lb[1].x, lb[1].y, lb[1].z, lb[1].w };

        unsigned pn = 0, tn = 0, vn = 0;
#pragma unroll
        for (int j = 0; j < 8; ++j) {
            const float l0 = fl[3 * j + 0];
            const float l1 = fl[3 * j + 1];
            const float l2 = fl[3 * j + 2];
            const int lab = labs[j];

            const bool valid = (lab != -100);
            const int ls = valid ? lab : 0;

            const float mx = fmaxf(l0, fmaxf(l1, l2));
            const float se = __expf(l0 - mx) + __expf(l1 - mx) + __expf(l2 - mx);
            const float lse = mx + __logf(se);
            const float lpick = (ls == 0 ? l0 : (ls == 1 ? l1 : l2)) - lse;
            const float w = (ls == 0) ? 0.1f : 5.0f;
            bsum += valid ? (-w * lpick) : 0.f;
            vcnt += valid ? 1 : 0;

            // argmax first-occurrence: pred>=1 iff max(l1,l2) > l0
            pn |= (unsigned)(fmaxf(l1, l2) > l0) << j;
            tn |= (unsigned)(lab >= 1) << j;          // -100 excluded
            vn |= (unsigned)valid << j;
        }

        // byte k covers positions 4k..4k+3: low nibble psw, high nibble tsw
        const unsigned b0 = (pn & 0xF) | ((tn & 0xF) << 4);
        const unsigned b1 = ((pn >> 4) & 0xF) | (((tn >> 4) & 0xF) << 4);
        const unsigned vb = (vn & 0xF) | (((vn >> 4) & 0xF) << 8);
        pt16[o * BLOCK + tid] = (u16)(b0 | (b1 << 8));
        v16 [o * BLOCK + tid] = (u16)vb;
    }

    // block reduce -> per-block partial (no atomics)
#pragma unroll
    for (int off = 32; off; off >>= 1) {
        bsum += __shfl_down(bsum, off);
        vcnt += __shfl_down(vcnt, off);
    }
    __shared__ float wb[BLOCK / 64];
    __shared__ int   wv[BLOCK / 64];
    if ((tid & 63) == 0) { wb[wave] = bsum; wv[wave] = vcnt; }
    __syncthreads();
    if (tid == 0) {
        double s = 0.0; int cc = 0;
#pragma unroll
        for (int i = 0; i < BLOCK / 64; ++i) { s += (double)wb[i]; cc += wv[i]; }
        pbsum[blockIdx.x] = s;
        pvcnt[blockIdx.x] = cc;
    }
}

// ---------------- K2: per-row window + counts ----------------
// One block per row; thread t owns 64-pos group t (16 bytes of each mask array).
__global__ __launch_bounds__(BLOCK) void k2_window(
    const u8* __restrict__ pt_b, const u8* __restrict__ v_b,
    float* __restrict__ adj_row)
{
    const int row = blockIdx.x;
    const int t = threadIdx.x;

    // assemble this group's masks from 16 bytes (4 words x 16 positions)
    const int4 ptq = *(const int4*)(pt_b + (long long)row * 4096 + 16 * t);
    const int4 vq  = *(const int4*)(v_b  + (long long)row * 4096 + 16 * t);
    const unsigned pw[4] = { (unsigned)ptq.x, (unsigned)ptq.y, (unsigned)ptq.z, (unsigned)ptq.w };
    const unsigned vw[4] = { (unsigned)vq.x,  (unsigned)vq.y,  (unsigned)vq.z,  (unsigned)vq.w };

    u64 pm = 0, tm = 0, vm = 0;
#pragma unroll
    for (int wd = 0; wd < 4; ++wd) {
        const unsigned w = pw[wd];
        const unsigned v = vw[wd];
        const unsigned p16 = (w & 0xF) | ((w >> 8) & 0xF) << 4 | ((w >> 16) & 0xF) << 8 | ((w >> 24) & 0xF) << 12;
        const unsigned t16 = ((w >> 4) & 0xF) | ((w >> 12) & 0xF) << 4 | ((w >> 20) & 0xF) << 8 | ((w >> 28) & 0xF) << 12;
        const unsigned v16w = (v & 0xF) | ((v >> 8) & 0xF) << 4 | ((v >> 16) & 0xF) << 8 | ((v >> 24) & 0xF) << 12;
        pm |= (u64)p16 << (16 * wd);
        tm |= (u64)t16 << (16 * wd);
        vm |= (u64)v16w << (16 * wd);
    }

    __shared__ u64 pmS[BLOCK], tmS[BLOCK];
    pmS[t] = pm; tmS[t] = tm;
    __syncthreads();

    const u64 pp = (t > 0)         ? pmS[t - 1] : 0ULL;
    const u64 pn = (t < BLOCK - 1) ? pmS[t + 1] : 0ULL;
    const u64 tp = (t > 0)         ? tmS[t - 1] : 0ULL;
    const u64 tn = (t < BLOCK - 1) ? tmS[t + 1] : 0ULL;

    u64 pnear = pm, tnear = tm;
#pragma unroll
    for (int k = 1; k <= TOL; ++k) {
        pnear |= (pm << k) | (pm >> k) | (pp >> (64 - k)) | (pn << (64 - k));
        tnear |= (tm << k) | (tm >> k) | (tp >> (64 - k)) | (tn << (64 - k));
    }

    int reward  = __popcll(tm & pnear);        // true_sw implies valid
    int penalty = __popcll(pm & ~tnear & vm);  // gated by valid
    int ht = (tm != 0ULL) ? 1 : 0;

#pragma unroll
    for (int off = 32; off; off >>= 1) {
        reward  += __shfl_down(reward, off);
        penalty += __shfl_down(penalty, off);
        ht      |= __shfl_down(ht, off);
    }
    __shared__ int rs[BLOCK / 64], ps[BLOCK / 64], hs[BLOCK / 64];
    const int wave = t >> 6;
    if ((t & 63) == 0) { rs[wave] = reward; ps[wave] = penalty; hs[wave] = ht; }
    __syncthreads();
    if (t == 0) {
        int R = 0, P = 0, H = 0;
#pragma unroll
        for (int i = 0; i < BLOCK / 64; ++i) { R += rs[i]; P += ps[i]; H |= hs[i]; }
        adj_row[row] = -2.0f * (float)R + (H ? 1.5f * (float)P : 0.0f);  // exact ints
    }
}

// ---------------- K3: final reduce (one block) ----------------
__global__ __launch_bounds__(BLOCK) void k3_reduce(
    const double* __restrict__ pbsum, const int* __restrict__ pvcnt, int nblocks,
    const float* __restrict__ adj_row, int nrows,
    float* __restrict__ out)
{
    const int t = threadIdx.x;
    double s = 0.0, a = 0.0;
    long long c = 0;
    for (int i = t; i < nblocks; i += BLOCK) { s += pbsum[i]; c += (long long)pvcnt[i]; }
    for (int i = t; i < nrows; i += BLOCK) a += (double)adj_row[i];

#pragma unroll
    for (int off = 32; off; off >>= 1) {
        s += __shfl_down(s, off);
        a += __shfl_down(a, off);
        c += __shfl_down(c, off);
    }
    __shared__ double ss[BLOCK / 64], as[BLOCK / 64];
    __shared__ long long cs[BLOCK / 64];
    const int wave = t >> 6;
    if ((t & 63) == 0) { ss[wave] = s; as[wave] = a; cs[wave] = c; }
    __syncthreads();
    if (t == 0) {
        double S = 0.0, A = 0.0; long long C = 0;
#pragma unroll
        for (int i = 0; i < BLOCK / 64; ++i) { S += ss[i]; A += as[i]; C += cs[i]; }
        out[0] = (float)((S + A) / (double)C);
    }
}

extern "C" void kernel_launch(void* const* d_in, const int* in_sizes, int n_in,
                              void* d_out, int out_size, void* d_ws, size_t ws_size,
                              hipStream_t stream) {
    const float* logits = (const float*)d_in[0];
    const int*   labels = (const int*)d_in[1];
    float* out = (float*)d_out;

    const long long BS = in_sizes[1];        // B*S = 8388608
    const int B = 512;                       // rows (S=16384 -> 256 groups/row)
    const long long nOct = BS / (BLOCK * 8); // 4096 (2048 positions per oct-group)

    char* ws = (char*)d_ws;
    u16* pt16 = (u16*)ws;                                // BS/8 u16 = 2 MB
    u16* v16  = pt16 + BS / 8;                           // 2 MB
    double* pbsum = (double*)(v16 + BS / 8);             // 16 KB
    int* pvcnt    = (int*)(pbsum + GRID1);               // 8 KB
    float* adjrow = (float*)(pvcnt + GRID1);             // 2 KB

    k1_oct<<<GRID1, BLOCK, 0, stream>>>(
        logits, labels, pt16, v16, pbsum, pvcnt, nOct);
    k2_window<<<B, BLOCK, 0, stream>>>((const u8*)pt16, (const u8*)v16, adjrow);
    k3_reduce<<<1, BLOCK, 0, stream>>>(pbsum, pvcnt, GRID1, adjrow, B, out);
}